// Round 2
// baseline (114.198 us; speedup 1.0000x reference)
//
#include <hip/hip_runtime.h>

#define BATCH 1024
#define NCOLS 8192
#define NROWS 8192
#define NNZPR 32
#define BT    128   // batch tile for the main spmm kernel

// ---------------------------------------------------------------------------
// Kernel 1: transpose X (BATCH x NCOLS) -> XT (NCOLS x BATCH), 64x64 LDS tiles
// ---------------------------------------------------------------------------
__global__ __launch_bounds__(256) void transpose_x(const float* __restrict__ x,
                                                   float* __restrict__ xt) {
    __shared__ float tile[64][65];
    const int c0 = blockIdx.x * 64;
    const int b0 = blockIdx.y * 64;
    const int tx = threadIdx.x & 63;
    const int ty = threadIdx.x >> 6;

#pragma unroll
    for (int i = 0; i < 16; ++i) {
        const int b = ty + i * 4;
        tile[b][tx] = x[(size_t)(b0 + b) * NCOLS + c0 + tx];
    }
    __syncthreads();
#pragma unroll
    for (int i = 0; i < 16; ++i) {
        const int c = ty + i * 4;
        xt[(size_t)(c0 + c) * BATCH + b0 + tx] = tile[tx][c];
    }
}

// ---------------------------------------------------------------------------
// Kernel 2 (main): 64-row x 128-batch tiles on transposed XT.
//   - (col,val) fused as int2 in LDS -> single ds_read_b64 per nnz
//   - float2 gather: 512B per wave-load
//   - grid bid = rt*8 + bt  =>  XCD (bid%8) == bt: each XCD's gather working
//     set is XT[:, bt*128 : bt*128+128] = 4 MiB = exactly its private L2.
// ---------------------------------------------------------------------------
__global__ __launch_bounds__(256) void spmm_v2(const float* __restrict__ xt,
                                               const float* __restrict__ vals,
                                               const int*   __restrict__ cols,
                                               float* __restrict__ out) {
    // phase 1: 2048 int2 pairs (16 KiB); phase 2: 128x65 f32 tile (33.3 KiB)
    __shared__ __align__(16) char smem[BT * 65 * 4];
    int2* s_pair = (int2*)smem;

    const int bid  = blockIdx.x;
    const int bt   = bid & 7;        // batch tile -> XCD id
    const int rt   = bid >> 3;       // row tile 0..127
    const int t    = threadIdx.x;
    const int lane = t & 63;
    const int wave = t >> 6;

    const int nnzbase = rt * 64 * NNZPR;
    for (int i = t; i < 64 * NNZPR; i += 256) {
        int2 p;
        p.x = cols[nnzbase + i];
        p.y = __float_as_int(vals[nnzbase + i]);
        s_pair[i] = p;
    }
    __syncthreads();

    // this lane's 2 batches: bt*128 + 2*lane, +1  (8B-aligned in XT rows)
    const float* __restrict__ xb = xt + (size_t)bt * BT + 2 * lane;

    const int rbase = wave * 16;     // each wave owns 16 rows
    float2 acc[16];
#pragma unroll
    for (int i = 0; i < 16; ++i) { acc[i].x = 0.f; acc[i].y = 0.f; }

    for (int i = 0; i < 16; ++i) {
        const int p0 = (rbase + i) * NNZPR;
        float ax = 0.f, ay = 0.f;
#pragma unroll
        for (int k = 0; k < NNZPR; ++k) {
            const int2  pr = s_pair[p0 + k];            // ds_read_b64
            const float v  = __int_as_float(pr.y);
            const float2 xv = *(const float2*)(xb + (size_t)pr.x * BATCH);
            ax += xv.x * v;
            ay += xv.y * v;
        }
        acc[i].x = ax; acc[i].y = ay;
    }
    __syncthreads();   // done with s_pair; reuse LDS as transpose tile

    float* tile = (float*)smem;      // [128][65]
#pragma unroll
    for (int i = 0; i < 16; ++i) {
        tile[(2 * lane + 0) * 65 + rbase + i] = acc[i].x;  // 2-way bank alias: free
        tile[(2 * lane + 1) * 65 + rbase + i] = acc[i].y;
    }
    __syncthreads();

    const int r  = t & 63;
    const int b0 = t >> 6;
    const size_t obase = (size_t)(bt * BT) * NROWS + (size_t)rt * 64;
#pragma unroll
    for (int p = 0; p < 32; ++p) {
        const int b = b0 + p * 4;
        out[obase + (size_t)b * NROWS + r] = tile[b * 65 + r];  // 256B/wave store
    }
}

// ---------------------------------------------------------------------------
// Fallback (ws too small for XT): scalar gather straight from X. Correctness
// insurance only.
// ---------------------------------------------------------------------------
__global__ __launch_bounds__(256) void spmm_fallback(const float* __restrict__ x,
                                                     const float* __restrict__ vals,
                                                     const int*   __restrict__ cols,
                                                     float* __restrict__ out) {
    __shared__ __align__(16) char smem[64 * 65 * 4];
    int*   s_col = (int*)smem;
    float* s_val = (float*)(smem + 64 * 32 * 4);

    const int bid  = blockIdx.x;
    const int bt   = bid & 15;
    const int rt   = bid >> 4;
    const int t    = threadIdx.x;
    const int lane = t & 63;
    const int wave = t >> 6;

    const int nnzbase = rt * 64 * NNZPR;
    for (int i = t; i < 64 * NNZPR; i += 256) {
        s_col[i] = cols[nnzbase + i];
        s_val[i] = vals[nnzbase + i];
    }
    __syncthreads();

    const int b = bt * 64 + lane;
    const float* __restrict__ xb = x + (size_t)b * NCOLS;

    const int rbase = wave * 16;
    float acc[16];
#pragma unroll
    for (int i = 0; i < 16; ++i) acc[i] = 0.f;

    for (int i = 0; i < 16; ++i) {
        const int p = (rbase + i) * NNZPR;
        float a = 0.f;
#pragma unroll
        for (int k = 0; k < NNZPR; ++k)
            a += xb[s_col[p + k]] * s_val[p + k];
        acc[i] = a;
    }
    __syncthreads();

    float* tile = (float*)smem;
#pragma unroll
    for (int i = 0; i < 16; ++i)
        tile[lane * 65 + rbase + i] = acc[i];
    __syncthreads();

    const int rl  = t & 63;
    const int bl0 = t >> 6;
    const size_t obase = (size_t)(bt * 64) * NROWS + (size_t)rt * 64;
#pragma unroll
    for (int p = 0; p < 16; ++p) {
        const int bl = bl0 + p * 4;
        out[obase + (size_t)bl * NROWS + rl] = tile[bl * 65 + rl];
    }
}

extern "C" void kernel_launch(void* const* d_in, const int* in_sizes, int n_in,
                              void* d_out, int out_size, void* d_ws, size_t ws_size,
                              hipStream_t stream) {
    const float* x    = (const float*)d_in[0];
    const float* vals = (const float*)d_in[1];
    // d_in[2] = rows (repeat(arange(NROWS), 32)) -- structure known, unused
    const int*   cols = (const int*)d_in[3];
    float* out = (float*)d_out;

    const size_t xt_bytes = (size_t)NCOLS * BATCH * sizeof(float);
    if (ws_size >= xt_bytes) {
        float* xt = (float*)d_ws;
        dim3 tgrid(NCOLS / 64, BATCH / 64);
        transpose_x<<<tgrid, 256, 0, stream>>>(x, xt);
        spmm_v2<<<(NROWS / 64) * (BATCH / BT), 256, 0, stream>>>(xt, vals, cols, out);
    } else {
        spmm_fallback<<<(NROWS / 64) * (BATCH / 64), 256, 0, stream>>>(
            x, vals, cols, out);
    }
}

// Round 3
// 82.846 us; speedup vs baseline: 1.3784x; 1.3784x over previous
//
#include <hip/hip_runtime.h>

#define BATCH 1024
#define NCOLS 8192
#define NROWS 8192
#define NNZPR 32
#define BT    128   // batch tile (128 batches = 2 per lane, float2 gathers)
#define ROWT  32    // row tile (keeps LDS at 16.9 KB -> 8 blocks/CU)

// ---------------------------------------------------------------------------
// Kernel 1: transpose X (BATCH x NCOLS) -> XT (NCOLS x BATCH), 64x64 LDS tiles
// ~12 us, near HBM floor for 64 MiB of traffic. Unchanged.
// ---------------------------------------------------------------------------
__global__ __launch_bounds__(256) void transpose_x(const float* __restrict__ x,
                                                   float* __restrict__ xt) {
    __shared__ float tile[64][65];
    const int c0 = blockIdx.x * 64;
    const int b0 = blockIdx.y * 64;
    const int tx = threadIdx.x & 63;
    const int ty = threadIdx.x >> 6;

#pragma unroll
    for (int i = 0; i < 16; ++i) {
        const int b = ty + i * 4;
        tile[b][tx] = x[(size_t)(b0 + b) * NCOLS + c0 + tx];
    }
    __syncthreads();
#pragma unroll
    for (int i = 0; i < 16; ++i) {
        const int c = ty + i * 4;
        xt[(size_t)(c0 + c) * BATCH + b0 + tx] = tile[tx][c];
    }
}

// ---------------------------------------------------------------------------
// Kernel 2 (main): 32-row x 128-batch tiles on XT.
//   - int2 (col*1024, val) pairs in LDS: one ds_read_b64, no per-lane mul
//   - float2 gather: 512 B per wave-load
//   - LDS 16896 B -> 8 blocks/CU = 32 waves/CU (round-1 occupancy)
//   - bid = rt*8 + bt: XCD (bid%8) == bt -> per-XCD XT slice = 4 MiB = its L2
//   - output transposed via conflict-free [64][33][2] LDS layout
// ---------------------------------------------------------------------------
__global__ __launch_bounds__(256) void spmm_v3(const float* __restrict__ xt,
                                               const float* __restrict__ vals,
                                               const int*   __restrict__ cols,
                                               float* __restrict__ out) {
    // phase 1: 1024 int2 pairs (8 KiB); phase 2: float[64][33][2] (16896 B)
    __shared__ __align__(16) char smem[64 * 33 * 2 * 4];
    int2* s_pair = (int2*)smem;

    const int bid  = blockIdx.x;
    const int bt   = bid & 7;        // batch tile -> XCD id
    const int rt   = bid >> 3;       // row tile 0..255
    const int t    = threadIdx.x;
    const int lane = t & 63;
    const int wave = t >> 6;

    const int nnzbase = rt * ROWT * NNZPR;   // rt*1024
    for (int i = t; i < ROWT * NNZPR; i += 256) {
        int2 p;
        p.x = cols[nnzbase + i] * BATCH;     // pre-multiplied element offset
        p.y = __float_as_int(vals[nnzbase + i]);
        s_pair[i] = p;
    }
    __syncthreads();

    // this lane's 2 batches: bt*128 + 2*lane, +1 (8B-aligned in XT rows)
    const float* __restrict__ xb = xt + (size_t)bt * BT + 2 * lane;

    const int rbase = wave * 8;              // each wave owns 8 rows
    float2 acc[8];

    for (int i = 0; i < 8; ++i) {
        const int p0 = (rbase + i) * NNZPR;
        float ax0 = 0.f, ax1 = 0.f, ay0 = 0.f, ay1 = 0.f;
#pragma unroll
        for (int k = 0; k < NNZPR; k += 2) {
            const int2 pa = s_pair[p0 + k];
            const int2 pb = s_pair[p0 + k + 1];
            const float va = __int_as_float(pa.y);
            const float vb = __int_as_float(pb.y);
            const float2 xa = *(const float2*)(xb + pa.x);
            const float2 xv = *(const float2*)(xb + pb.x);
            ax0 += xa.x * va;  ay0 += xa.y * va;
            ax1 += xv.x * vb;  ay1 += xv.y * vb;
        }
        acc[i].x = ax0 + ax1;
        acc[i].y = ay0 + ay1;
    }
    __syncthreads();   // done with s_pair; reuse LDS as transpose tile

    // layout: tile[lane64][row33][pair2] -- ds_write_b64 hits all 32 banks
    // per 16 lanes (optimal 4-cycle wave write); readout is 2-way (free)
    float* tile = (float*)smem;
#pragma unroll
    for (int i = 0; i < 8; ++i)
        *(float2*)&tile[(lane * 33 + rbase + i) * 2] = acc[i];
    __syncthreads();

    const int r  = t & 31;           // row within tile
    const int bq = t >> 5;           // 0..7
    const size_t obase = (size_t)(bt * BT) * NROWS + (size_t)rt * ROWT;
#pragma unroll
    for (int p = 0; p < 16; ++p) {
        const int b = bq + p * 8;    // batch within tile
        // half-wave writes 128 B contiguous in r
        out[obase + (size_t)b * NROWS + r] = tile[((b >> 1) * 33 + r) * 2 + (b & 1)];
    }
}

// ---------------------------------------------------------------------------
// Fallback (ws too small for XT): scalar gather straight from X.
// ---------------------------------------------------------------------------
__global__ __launch_bounds__(256) void spmm_fallback(const float* __restrict__ x,
                                                     const float* __restrict__ vals,
                                                     const int*   __restrict__ cols,
                                                     float* __restrict__ out) {
    __shared__ __align__(16) char smem[64 * 65 * 4];
    int*   s_col = (int*)smem;
    float* s_val = (float*)(smem + 64 * 32 * 4);

    const int bid  = blockIdx.x;
    const int bt   = bid & 15;
    const int rt   = bid >> 4;
    const int t    = threadIdx.x;
    const int lane = t & 63;
    const int wave = t >> 6;

    const int nnzbase = rt * 64 * NNZPR;
    for (int i = t; i < 64 * NNZPR; i += 256) {
        s_col[i] = cols[nnzbase + i];
        s_val[i] = vals[nnzbase + i];
    }
    __syncthreads();

    const int b = bt * 64 + lane;
    const float* __restrict__ xb = x + (size_t)b * NCOLS;

    const int rbase = wave * 16;
    float acc[16];
#pragma unroll
    for (int i = 0; i < 16; ++i) acc[i] = 0.f;

    for (int i = 0; i < 16; ++i) {
        const int p = (rbase + i) * NNZPR;
        float a = 0.f;
#pragma unroll
        for (int k = 0; k < NNZPR; ++k)
            a += xb[s_col[p + k]] * s_val[p + k];
        acc[i] = a;
    }
    __syncthreads();

    float* tile = (float*)smem;
#pragma unroll
    for (int i = 0; i < 16; ++i)
        tile[lane * 65 + rbase + i] = acc[i];
    __syncthreads();

    const int rl  = t & 63;
    const int bl0 = t >> 6;
    const size_t obase = (size_t)(bt * 64) * NROWS + (size_t)rt * 64;
#pragma unroll
    for (int p = 0; p < 16; ++p) {
        const int bl = bl0 + p * 4;
        out[obase + (size_t)bl * NROWS + rl] = tile[bl * 65 + rl];
    }
}

extern "C" void kernel_launch(void* const* d_in, const int* in_sizes, int n_in,
                              void* d_out, int out_size, void* d_ws, size_t ws_size,
                              hipStream_t stream) {
    const float* x    = (const float*)d_in[0];
    const float* vals = (const float*)d_in[1];
    // d_in[2] = rows (repeat(arange(NROWS), 32)) -- structure known, unused
    const int*   cols = (const int*)d_in[3];
    float* out = (float*)d_out;

    const size_t xt_bytes = (size_t)NCOLS * BATCH * sizeof(float);
    if (ws_size >= xt_bytes) {
        float* xt = (float*)d_ws;
        dim3 tgrid(NCOLS / 64, BATCH / 64);
        transpose_x<<<tgrid, 256, 0, stream>>>(x, xt);
        spmm_v3<<<(NROWS / ROWT) * (BATCH / BT), 256, 0, stream>>>(xt, vals, cols, out);
    } else {
        spmm_fallback<<<(NROWS / 64) * (BATCH / 64), 256, 0, stream>>>(
            x, vals, cols, out);
    }
}

// Round 4
// 76.368 us; speedup vs baseline: 1.4954x; 1.0848x over previous
//
#include <hip/hip_runtime.h>

#define BATCH 1024
#define NCOLS 8192
#define NROWS 8192
#define NNZPR 32
#define BT2   128   // batches per block (half-wave float4 = 128 floats/row)
#define RB    16    // rows per block

// ---------------------------------------------------------------------------
// Kernel 1: transpose X (BATCH x NCOLS) -> XT (NCOLS x BATCH). ~11-12 us,
// near HBM floor for 64 MiB traffic. Unchanged (known good).
// ---------------------------------------------------------------------------
__global__ __launch_bounds__(256) void transpose_x(const float* __restrict__ x,
                                                   float* __restrict__ xt) {
    __shared__ float tile[64][65];
    const int c0 = blockIdx.x * 64;
    const int b0 = blockIdx.y * 64;
    const int tx = threadIdx.x & 63;
    const int ty = threadIdx.x >> 6;

#pragma unroll
    for (int i = 0; i < 16; ++i) {
        const int b = ty + i * 4;
        tile[b][tx] = x[(size_t)(b0 + b) * NCOLS + c0 + tx];
    }
    __syncthreads();
#pragma unroll
    for (int i = 0; i < 16; ++i) {
        const int c = ty + i * 4;
        xt[(size_t)(c0 + c) * BATCH + b0 + tx] = tile[tx][c];
    }
}

// ---------------------------------------------------------------------------
// Kernel 2 (main): 16-row x 128-batch tiles on XT.
//   - half-wave = one row: lanes 0-31 gather 512B of row A, 32-63 row B
//     -> one global_load_dwordx4 moves 1 KiB/wave (16 B/lane, max coalescing)
//   - metadata: 2x ds_read_b128 (int4 = 2 premultiplied (col*1024,val) pairs)
//     broadcast per half-wave; 4 independent float4 loads per group
//   - latency-robust: even ZERO-ILP serial groups -> ~19us; TLP (32 waves/CU)
//     covers the rest. No reliance on compiler software pipelining (r3 bug).
//   - bid = rt*8 + bt: XCD (bid%8)==bt -> per-XCD XT slice 4 MiB = its L2
// ---------------------------------------------------------------------------
__global__ __launch_bounds__(256, 8) void spmm_v4(const float* __restrict__ xt,
                                                  const float* __restrict__ vals,
                                                  const int*   __restrict__ cols,
                                                  float* __restrict__ out) {
    // phase 1: 512 int2 pairs (4 KiB); phase 2: float[16][129] (8256 B)
    __shared__ __align__(16) char smem[RB * 129 * 4];
    int2* s_pair = (int2*)smem;

    const int bid = blockIdx.x;
    const int bt  = bid & 7;         // batch tile -> XCD id
    const int rt  = bid >> 3;        // row tile 0..511
    const int t   = threadIdx.x;

    const int nnzbase = rt * RB * NNZPR;   // rt*512
    for (int i = t; i < RB * NNZPR; i += 256) {
        int2 p;
        p.x = cols[nnzbase + i] * BATCH;   // premultiplied element offset
        p.y = __float_as_int(vals[nnzbase + i]);
        s_pair[i] = p;
    }
    __syncthreads();

    const int hw = t >> 5;           // half-wave id 0..7 (owns rows hw*2, hw*2+1)
    const int sl = t & 31;           // sub-lane: batch quad within the row
    const float* __restrict__ xb = xt + bt * BT2 + sl * 4;

    float4 acc0 = {0.f, 0.f, 0.f, 0.f};
    float4 acc1 = {0.f, 0.f, 0.f, 0.f};

    // ---- row A: pairs [hw*64 .. hw*64+32) ----
    {
        const int pb = hw * 2 * NNZPR;
#pragma unroll
        for (int g = 0; g < 8; ++g) {
            const int4 ma = *(const int4*)&s_pair[pb + g * 4];
            const int4 mb = *(const int4*)&s_pair[pb + g * 4 + 2];
            const float4 x0 = *(const float4*)(xb + ma.x);
            const float4 x1 = *(const float4*)(xb + ma.z);
            const float4 x2 = *(const float4*)(xb + mb.x);
            const float4 x3 = *(const float4*)(xb + mb.z);
            const float v0 = __int_as_float(ma.y);
            const float v1 = __int_as_float(ma.w);
            const float v2 = __int_as_float(mb.y);
            const float v3 = __int_as_float(mb.w);
            acc0.x += x0.x * v0; acc0.y += x0.y * v0; acc0.z += x0.z * v0; acc0.w += x0.w * v0;
            acc0.x += x1.x * v1; acc0.y += x1.y * v1; acc0.z += x1.z * v1; acc0.w += x1.w * v1;
            acc0.x += x2.x * v2; acc0.y += x2.y * v2; acc0.z += x2.z * v2; acc0.w += x2.w * v2;
            acc0.x += x3.x * v3; acc0.y += x3.y * v3; acc0.z += x3.z * v3; acc0.w += x3.w * v3;
        }
    }
    // ---- row B: pairs [hw*64+32 .. hw*64+64) ----
    {
        const int pb = (hw * 2 + 1) * NNZPR;
#pragma unroll
        for (int g = 0; g < 8; ++g) {
            const int4 ma = *(const int4*)&s_pair[pb + g * 4];
            const int4 mb = *(const int4*)&s_pair[pb + g * 4 + 2];
            const float4 x0 = *(const float4*)(xb + ma.x);
            const float4 x1 = *(const float4*)(xb + ma.z);
            const float4 x2 = *(const float4*)(xb + mb.x);
            const float4 x3 = *(const float4*)(xb + mb.z);
            const float v0 = __int_as_float(ma.y);
            const float v1 = __int_as_float(ma.w);
            const float v2 = __int_as_float(mb.y);
            const float v3 = __int_as_float(mb.w);
            acc1.x += x0.x * v0; acc1.y += x0.y * v0; acc1.z += x0.z * v0; acc1.w += x0.w * v0;
            acc1.x += x1.x * v1; acc1.y += x1.y * v1; acc1.z += x1.z * v1; acc1.w += x1.w * v1;
            acc1.x += x2.x * v2; acc1.y += x2.y * v2; acc1.z += x2.z * v2; acc1.w += x2.w * v2;
            acc1.x += x3.x * v3; acc1.y += x3.y * v3; acc1.z += x3.z * v3; acc1.w += x3.w * v3;
        }
    }
    __syncthreads();   // done with s_pair; reuse LDS as output tile

    // tile[r][b], r-major, row stride 129 (readout stride 129 % 32 == 1:
    // conflict-free). Writes are 4-way aliased but tiny volume.
    float* tile = (float*)smem;
    const int r0 = hw * 2;
#pragma unroll
    for (int j = 0; j < 4; ++j) {
        tile[(r0 + 0) * 129 + sl * 4 + j] = (&acc0.x)[j];
        tile[(r0 + 1) * 129 + sl * 4 + j] = (&acc1.x)[j];
    }
    __syncthreads();

    const int rr = t & 15;           // row within tile
    const int bc = t >> 4;           // 0..15
    const size_t obase = (size_t)(bt * BT2) * NROWS + (size_t)(rt * RB);
#pragma unroll
    for (int p = 0; p < 8; ++p) {
        const int b = bc + p * 16;   // batch within tile
        out[obase + (size_t)b * NROWS + rr] = tile[rr * 129 + b];
    }
}

// ---------------------------------------------------------------------------
// Fallback (ws too small for XT): scalar gather straight from X (round-1
// known-good). Correctness insurance only.
// ---------------------------------------------------------------------------
__global__ __launch_bounds__(256) void spmm_fallback(const float* __restrict__ x,
                                                     const float* __restrict__ vals,
                                                     const int*   __restrict__ cols,
                                                     float* __restrict__ out) {
    __shared__ __align__(16) char smem[64 * 65 * 4];
    int*   s_col = (int*)smem;
    float* s_val = (float*)(smem + 64 * 32 * 4);

    const int bid  = blockIdx.x;
    const int bt   = bid & 15;
    const int rt   = bid >> 4;
    const int t    = threadIdx.x;
    const int lane = t & 63;
    const int wave = t >> 6;

    const int nnzbase = rt * 64 * NNZPR;
    for (int i = t; i < 64 * NNZPR; i += 256) {
        s_col[i] = cols[nnzbase + i];
        s_val[i] = vals[nnzbase + i];
    }
    __syncthreads();

    const int b = bt * 64 + lane;
    const float* __restrict__ xb = x + (size_t)b * NCOLS;

    const int rbase = wave * 16;
    float acc[16];
#pragma unroll
    for (int i = 0; i < 16; ++i) acc[i] = 0.f;

    for (int i = 0; i < 16; ++i) {
        const int p = (rbase + i) * NNZPR;
        float a = 0.f;
#pragma unroll
        for (int k = 0; k < NNZPR; ++k)
            a += xb[s_col[p + k]] * s_val[p + k];
        acc[i] = a;
    }
    __syncthreads();

    float* tile = (float*)smem;
#pragma unroll
    for (int i = 0; i < 16; ++i)
        tile[lane * 65 + rbase + i] = acc[i];
    __syncthreads();

    const int rl  = t & 63;
    const int bl0 = t >> 6;
    const size_t obase = (size_t)(bt * 64) * NROWS + (size_t)rt * 64;
#pragma unroll
    for (int p = 0; p < 16; ++p) {
        const int bl = bl0 + p * 4;
        out[obase + (size_t)bl * NROWS + rl] = tile[bl * 65 + rl];
    }
}

extern "C" void kernel_launch(void* const* d_in, const int* in_sizes, int n_in,
                              void* d_out, int out_size, void* d_ws, size_t ws_size,
                              hipStream_t stream) {
    const float* x    = (const float*)d_in[0];
    const float* vals = (const float*)d_in[1];
    // d_in[2] = rows (repeat(arange(NROWS), 32)) -- structure known, unused
    const int*   cols = (const int*)d_in[3];
    float* out = (float*)d_out;

    const size_t xt_bytes = (size_t)NCOLS * BATCH * sizeof(float);
    if (ws_size >= xt_bytes) {
        float* xt = (float*)d_ws;
        dim3 tgrid(NCOLS / 64, BATCH / 64);
        transpose_x<<<tgrid, 256, 0, stream>>>(x, xt);
        spmm_v4<<<(NROWS / RB) * (BATCH / BT2), 256, 0, stream>>>(xt, vals, cols, out);
    } else {
        spmm_fallback<<<(NROWS / 64) * (BATCH / 64), 256, 0, stream>>>(
            x, vals, cols, out);
    }
}